// Round 1
// baseline (5912.977 us; speedup 1.0000x reference)
//
#include <hip/hip_runtime.h>
#include <stdint.h>

// LSTM B=64,T=512,I=512,H=512. out hs[T,B,H] fp32.
// Persistent kernel: 4 batch-groups x 32 wgs (128 wgs, 256 thr each).
// Each wg: 16 batch rows x 16 h-columns (all 4 gates). Weights held in
// registers as bf16 MFMA B-fragments (K=1024 = [w_ih|w_hh]). Per step:
// stage A=[x_t|h] in LDS (bf16, XOR swizzle), 32x mfma_16x16x32_bf16/wave,
// in-wave i/f/g/o exchange via shfl_xor, h broadcast via agent-scope
// atomics + per-group counter barrier. fp32 cell state in registers.

#define BATCH 64
#define TSTEPS 512
#define IDIM 512
#define HDIM 512
#define KCAT 1024
#define WGS_PER_GROUP 32
#define NGROUPS 4
#define BB 16
#define NWG (WGS_PER_GROUP * NGROUPS)

typedef __attribute__((ext_vector_type(4))) float f32x4;
typedef __attribute__((ext_vector_type(8))) short bf16x8;

__device__ inline unsigned short f2bf(float f) {
  unsigned u = __builtin_bit_cast(unsigned, f);
  u = (u + 0x7fffu + ((u >> 16) & 1u)) >> 16;  // RNE
  return (unsigned short)u;
}

// returns a_idx from {a0,a1,a2,a3}
__device__ inline float pick4(int idx, float a0, float a1, float a2, float a3) {
  float lo = (idx & 1) ? a1 : a0;
  float hi = (idx & 1) ? a3 : a2;
  return (idx & 2) ? hi : lo;
}

__global__ void lstm_init(const float* __restrict__ b_ih, const float* __restrict__ b_hh,
                          float* __restrict__ bias, uint32_t* __restrict__ h0buf,
                          uint32_t* __restrict__ counters) {
  const int i = blockIdx.x * blockDim.x + threadIdx.x;
  if (i < 4 * HDIM) bias[i] = b_ih[i] + b_hh[i];
  for (int j = i; j < BATCH * HDIM / 2; j += 2048) h0buf[j] = 0u;  // zero h buffer 0
  if (i < 64) counters[i] = 0u;
}

__global__ __launch_bounds__(256, 1)
void lstm_persistent(const float* __restrict__ x,
                     const float* __restrict__ w_ih,
                     const float* __restrict__ w_hh,
                     const float* __restrict__ bias,
                     uint32_t* h_buf,        // [2][BATCH*HDIM/2] packed bf16 pairs
                     uint32_t* counters,     // [NGROUPS*16]
                     float* __restrict__ out) {
  __shared__ unsigned short A_lds[16 * KCAT];  // 32KB, XOR-swizzled rows

  const int wg = blockIdx.x;
  const int group = wg >> 5;        // /WGS_PER_GROUP
  const int wgg = wg & 31;
  const int b0 = group * BB;
  const int h0 = wgg * 16;
  const int tid = threadIdx.x;
  const int wave = tid >> 6;
  const int lane = tid & 63;

  // ---- one-time: load weight B-fragments into registers (bf16) ----
  // B-tile rows permuted: n = 4*type + dh, so a wave's 16 rows cover
  // {i,f,g,o} x 4 h-columns. Fragment: lane l holds rows n=l&15,
  // k = kt*32 + (l>>4)*8 + j  (j=0..7).
  const int nn = lane & 15;
  const int tt = nn >> 2;                    // gate type: 0=i 1=f 2=g 3=o
  const int hh = h0 + wave * 4 + (nn & 3);   // h column
  const int grow = tt * HDIM + hh;           // row in [0,2048)
  const int kg = (lane >> 4) * 8;
  bf16x8 breg[32];
#pragma unroll
  for (int kt = 0; kt < 32; ++kt) {
    const int k = kt * 32 + kg;
    const float* src = (k < IDIM) ? (w_ih + (size_t)grow * IDIM + k)
                                  : (w_hh + (size_t)grow * HDIM + (k - IDIM));
    bf16x8 v;
#pragma unroll
    for (int j = 0; j < 8; ++j) v[j] = (short)f2bf(src[j]);
    breg[kt] = v;
  }
  const float bval = bias[grow];

  // staging roles: thread -> (batch row sm, k-chunk sk)
  const int sm = tid >> 4;  // 0..15
  const int sk = tid & 15;  // 0..15

  // cell state: rows m_r = 4*(lane>>4)+r, col hh (4x type-redundant, consistent)
  float c0 = 0.f, c1 = 0.f, c2 = 0.f, c3 = 0.f;

  const int mrow = lane & 15;
  const int rswz = (mrow & 7) << 4;
  const int wswz = (sm & 7) << 4;
  uint32_t* cntp = counters + group * 16;

  for (int t = 0; t < TSTEPS; ++t) {
    const int cur = t & 1;

    // ---- stage A = [x_t | h_prev] into LDS (bf16, swizzled) ----
    {
      const float* xp = x + ((size_t)(b0 + sm) * TSTEPS + t) * IDIM + sk * 32;
#pragma unroll
      for (int q = 0; q < 4; ++q) {
        float4 fa = *(const float4*)(xp + q * 8);
        float4 fb = *(const float4*)(xp + q * 8 + 4);
        bf16x8 v;
        v[0] = (short)f2bf(fa.x); v[1] = (short)f2bf(fa.y);
        v[2] = (short)f2bf(fa.z); v[3] = (short)f2bf(fa.w);
        v[4] = (short)f2bf(fb.x); v[5] = (short)f2bf(fb.y);
        v[6] = (short)f2bf(fb.z); v[7] = (short)f2bf(fb.w);
        const int byte = (sm * 2048 + (sk * 4 + q) * 16) ^ wswz;
        *(bf16x8*)((char*)A_lds + byte) = v;
      }
      const uint32_t* hp = h_buf + (size_t)cur * (BATCH * HDIM / 2)
                         + ((b0 + sm) * HDIM + sk * 32) / 2;
      uint32_t hu[16];
#pragma unroll
      for (int j = 0; j < 16; ++j)
        hu[j] = __hip_atomic_load(hp + j, __ATOMIC_RELAXED, __HIP_MEMORY_SCOPE_AGENT);
#pragma unroll
      for (int q = 0; q < 4; ++q) {
        bf16x8 v;
#pragma unroll
        for (int j2 = 0; j2 < 4; ++j2) {
          uint32_t u = hu[q * 4 + j2];
          v[j2 * 2] = (short)(u & 0xffffu);
          v[j2 * 2 + 1] = (short)(u >> 16);
        }
        const int byte = (sm * 2048 + (64 + sk * 4 + q) * 16) ^ wswz;
        *(bf16x8*)((char*)A_lds + byte) = v;
      }
    }
    __syncthreads();

    // ---- GEMM: gates[16b x 16n] += A[16 x 1024] * W^T ----
    f32x4 acc0 = {0.f, 0.f, 0.f, 0.f}, acc1 = {0.f, 0.f, 0.f, 0.f};
#pragma unroll
    for (int kt = 0; kt < 32; kt += 2) {
      const int byteA = (mrow * 2048 + (kt * 4 + (lane >> 4)) * 16) ^ rswz;
      bf16x8 a0 = *(const bf16x8*)((const char*)A_lds + byteA);
      acc0 = __builtin_amdgcn_mfma_f32_16x16x32_bf16(a0, breg[kt], acc0, 0, 0, 0);
      const int byteB = (mrow * 2048 + ((kt + 1) * 4 + (lane >> 4)) * 16) ^ rswz;
      bf16x8 a1 = *(const bf16x8*)((const char*)A_lds + byteB);
      acc1 = __builtin_amdgcn_mfma_f32_16x16x32_bf16(a1, breg[kt + 1], acc1, 0, 0, 0);
    }

    // ---- elementwise: C/D layout col=lane&15 (our n), row=(lane>>4)*4+r ----
    float g0 = acc0[0] + acc1[0] + bval;
    float g1 = acc0[1] + acc1[1] + bval;
    float g2 = acc0[2] + acc1[2] + bval;
    float g3 = acc0[3] + acc1[3] + bval;
    // activate by OWN type (i,f,o: sigmoid; g: tanh), then exchange
    float v0 = (tt == 2) ? tanhf(g0) : 1.f / (1.f + expf(-g0));
    float v1 = (tt == 2) ? tanhf(g1) : 1.f / (1.f + expf(-g1));
    float v2 = (tt == 2) ? tanhf(g2) : 1.f / (1.f + expf(-g2));
    float v3 = (tt == 2) ? tanhf(g3) : 1.f / (1.f + expf(-g3));

    float hv0, hv1, hv2, hv3;
#define CELL_R(vr, cr, hvr)                                                  \
    {                                                                        \
      float e1 = __shfl_xor(vr, 4, 64);                                      \
      float e2 = __shfl_xor(vr, 8, 64);                                      \
      float e3 = __shfl_xor(e1, 8, 64);                                      \
      float iv = pick4(tt,     vr, e1, e2, e3);                              \
      float fv = pick4(tt ^ 1, vr, e1, e2, e3);                              \
      float gv = pick4(tt ^ 2, vr, e1, e2, e3);                              \
      float ov = pick4(tt ^ 3, vr, e1, e2, e3);                              \
      cr = fv * cr + iv * gv;                                                \
      hvr = ov * tanhf(cr);                                                  \
    }
    CELL_R(v0, c0, hv0)
    CELL_R(v1, c1, hv1)
    CELL_R(v2, c2, hv2)
    CELL_R(v3, c3, hv3)
#undef CELL_R

    // ---- stores: lane stores row m=4*(lane>>4)+tt, col hh ----
    const int m = 4 * (lane >> 4) + tt;
    const float hsel = pick4(tt, hv0, hv1, hv2, hv3);
    out[(size_t)t * (BATCH * HDIM) + (size_t)(b0 + m) * HDIM + hh] = hsel;

    unsigned hb = (unsigned)f2bf(hsel);
    unsigned ob = (unsigned)__shfl_xor((int)hb, 1, 64);
    if (!(lane & 1)) {
      uint32_t packed = hb | (ob << 16);
      uint32_t* hnp = h_buf + (size_t)(cur ^ 1) * (BATCH * HDIM / 2)
                    + (((b0 + m) * HDIM + hh) >> 1);
      __hip_atomic_store(hnp, packed, __ATOMIC_RELAXED, __HIP_MEMORY_SCOPE_AGENT);
    }

    // ---- per-group barrier (monotonic counter) ----
    __syncthreads();  // drains vmcnt: h stores at coherence point before arrival
    if (tid == 0) {
      __hip_atomic_fetch_add(cntp, 1u, __ATOMIC_RELEASE, __HIP_MEMORY_SCOPE_AGENT);
      const uint32_t tgt = (uint32_t)(WGS_PER_GROUP * (t + 1));
      while (__hip_atomic_load(cntp, __ATOMIC_ACQUIRE, __HIP_MEMORY_SCOPE_AGENT) < tgt)
        __builtin_amdgcn_s_sleep(2);
    }
    __syncthreads();
  }
}

extern "C" void kernel_launch(void* const* d_in, const int* in_sizes, int n_in,
                              void* d_out, int out_size, void* d_ws, size_t ws_size,
                              hipStream_t stream) {
  const float* x    = (const float*)d_in[0];
  const float* w_ih = (const float*)d_in[1];
  const float* w_hh = (const float*)d_in[2];
  const float* b_ih = (const float*)d_in[3];
  const float* b_hh = (const float*)d_in[4];
  float* out = (float*)d_out;

  char* ws = (char*)d_ws;
  float* bias = (float*)ws;                                  // 8KB
  uint32_t* h_buf = (uint32_t*)(ws + 8192);                  // 128KB (2 bufs)
  uint32_t* counters = (uint32_t*)(ws + 8192 + 131072);      // 256B

  lstm_init<<<8, 256, 0, stream>>>(b_ih, b_hh, bias, h_buf, counters);
  lstm_persistent<<<NWG, 256, 0, stream>>>(x, w_ih, w_hh, bias, h_buf, counters, out);
}

// Round 2
// 3589.051 us; speedup vs baseline: 1.6475x; 1.6475x over previous
//
#include <hip/hip_runtime.h>
#include <stdint.h>

// LSTM B=64,T=512,I=512,H=512. out hs[T,B,H] fp32.
// Persistent kernel: 4 batch-groups x 32 wgs (128 wgs, 256 thr each).
// Each wg: 16 batch rows x 16 h-columns (all 4 gates). Weights held in
// registers as bf16 MFMA B-fragments (K=1024 = [w_ih|w_hh]).
// h exchange: RELAXED agent-scope 64-bit atomics, self-describing words
// [h_pair:32 | tag:32] (tag = step). No acquire/release (no buffer_inv /
// buffer_wbl2 L2 maintenance), no counter barrier: consumers spin on the
// data tags themselves. Double-buffered by step parity.

#define BATCH 64
#define TSTEPS 512
#define IDIM 512
#define HDIM 512
#define KCAT 1024
#define WGS_PER_GROUP 32
#define NGROUPS 4
#define BB 16
#define NWG (WGS_PER_GROUP * NGROUPS)
#define HB_U64_PER_GROUP (BB * (HDIM / 2))   // 4096 u64 = 32KB

typedef __attribute__((ext_vector_type(4))) float f32x4;
typedef __attribute__((ext_vector_type(8))) short bf16x8;

__device__ inline unsigned short f2bf(float f) {
  unsigned u = __builtin_bit_cast(unsigned, f);
  u = (u + 0x7fffu + ((u >> 16) & 1u)) >> 16;  // RNE
  return (unsigned short)u;
}

__device__ inline float fast_sigmoid(float x) {
  return 1.f / (1.f + __expf(-x));
}
__device__ inline float fast_tanh(float x) {
  return 1.f - 2.f / (__expf(2.f * x) + 1.f);
}

// returns a_idx from {a0,a1,a2,a3}
__device__ inline float pick4(int idx, float a0, float a1, float a2, float a3) {
  float lo = (idx & 1) ? a1 : a0;
  float hi = (idx & 1) ? a3 : a2;
  return (idx & 2) ? hi : lo;
}

__global__ void lstm_init(const float* __restrict__ b_ih, const float* __restrict__ b_hh,
                          float* __restrict__ bias, uint64_t* __restrict__ h_buf) {
  const int i = blockIdx.x * blockDim.x + threadIdx.x;
  if (i < 4 * HDIM) bias[i] = b_ih[i] + b_hh[i];
  // zero both h buffers (tags -> 0, never matches an expected tag >= 1;
  // also clears stale tags from a previous graph replay)
  for (int j = i; j < 2 * NGROUPS * HB_U64_PER_GROUP; j += 2048) h_buf[j] = 0ull;
}

__global__ __launch_bounds__(256, 1)
void lstm_persistent(const float* __restrict__ x,
                     const float* __restrict__ w_ih,
                     const float* __restrict__ w_hh,
                     const float* __restrict__ bias,
                     uint64_t* h_buf,   // [2][NGROUPS][BB][HDIM/2] tagged pairs
                     float* __restrict__ out) {
  __shared__ unsigned short A_lds[16 * KCAT];  // 32KB, XOR-swizzled rows

  const int wg = blockIdx.x;
  const int group = wg >> 5;        // /WGS_PER_GROUP
  const int wgg = wg & 31;
  const int b0 = group * BB;
  const int h0 = wgg * 16;
  const int tid = threadIdx.x;
  const int wave = tid >> 6;
  const int lane = tid & 63;

  // ---- one-time: load weight B-fragments into registers (bf16) ----
  // B-tile rows permuted: n = 4*type + dh. Lane l holds rows n=l&15,
  // k = kt*32 + (l>>4)*8 + j (j=0..7).
  const int nn = lane & 15;
  const int tt = nn >> 2;                    // gate type: 0=i 1=f 2=g 3=o
  const int hh = h0 + wave * 4 + (nn & 3);   // h column
  const int grow = tt * HDIM + hh;           // row in [0,2048)
  const int kg = (lane >> 4) * 8;
  bf16x8 breg[32];
#pragma unroll
  for (int kt = 0; kt < 32; ++kt) {
    const int k = kt * 32 + kg;
    const float* src = (k < IDIM) ? (w_ih + (size_t)grow * IDIM + k)
                                  : (w_hh + (size_t)grow * HDIM + (k - IDIM));
    bf16x8 v;
#pragma unroll
    for (int j = 0; j < 8; ++j) v[j] = (short)f2bf(src[j]);
    breg[kt] = v;
  }
  const float bval = bias[grow];

  // staging roles: thread -> (batch row sm, k-chunk sk)
  const int sm = tid >> 4;  // 0..15
  const int sk = tid & 15;  // 0..15

  float c0 = 0.f, c1 = 0.f, c2 = 0.f, c3 = 0.f;

  const int mrow = lane & 15;
  const int rswz = (mrow & 7) << 4;
  const int wswz = (sm & 7) << 4;

  for (int t = 0; t < TSTEPS; ++t) {
    // ---- stage A = [x_t | h_prev] into LDS (bf16, swizzled) ----
    {
      const float* xp = x + ((size_t)(b0 + sm) * TSTEPS + t) * IDIM + sk * 32;
      // issue h loads first (longest latency)
      uint64_t hu[16];
      if (t > 0) {
        const uint64_t* hp = h_buf + ((size_t)(t & 1) * NGROUPS + group) * HB_U64_PER_GROUP
                           + sm * (HDIM / 2) + sk * 16;
#pragma unroll
        for (int j = 0; j < 16; ++j)
          hu[j] = __hip_atomic_load(hp + j, __ATOMIC_RELAXED, __HIP_MEMORY_SCOPE_AGENT);
#pragma unroll
        for (int j = 0; j < 16; ++j)
          while ((uint32_t)hu[j] != (uint32_t)t)
            hu[j] = __hip_atomic_load(hp + j, __ATOMIC_RELAXED, __HIP_MEMORY_SCOPE_AGENT);
      }
#pragma unroll
      for (int q = 0; q < 4; ++q) {
        float4 fa = *(const float4*)(xp + q * 8);
        float4 fb = *(const float4*)(xp + q * 8 + 4);
        bf16x8 v;
        v[0] = (short)f2bf(fa.x); v[1] = (short)f2bf(fa.y);
        v[2] = (short)f2bf(fa.z); v[3] = (short)f2bf(fa.w);
        v[4] = (short)f2bf(fb.x); v[5] = (short)f2bf(fb.y);
        v[6] = (short)f2bf(fb.z); v[7] = (short)f2bf(fb.w);
        const int byte = (sm * 2048 + (sk * 4 + q) * 16) ^ wswz;
        *(bf16x8*)((char*)A_lds + byte) = v;
      }
#pragma unroll
      for (int q = 0; q < 4; ++q) {
        bf16x8 v;
        if (t > 0) {
#pragma unroll
          for (int jj = 0; jj < 4; ++jj) {
            uint32_t u = (uint32_t)(hu[q * 4 + jj] >> 32);
            v[jj * 2] = (short)(u & 0xffffu);
            v[jj * 2 + 1] = (short)(u >> 16);
          }
        } else {
          v = (bf16x8)0;
        }
        const int byte = (sm * 2048 + (64 + sk * 4 + q) * 16) ^ wswz;
        *(bf16x8*)((char*)A_lds + byte) = v;
      }
    }
    __syncthreads();

    // ---- GEMM: gates[16b x 16n] += A[16 x 1024] * W^T ----
    f32x4 acc0 = {0.f, 0.f, 0.f, 0.f}, acc1 = {0.f, 0.f, 0.f, 0.f};
#pragma unroll
    for (int kt = 0; kt < 32; kt += 2) {
      const int byteA = (mrow * 2048 + (kt * 4 + (lane >> 4)) * 16) ^ rswz;
      bf16x8 a0 = *(const bf16x8*)((const char*)A_lds + byteA);
      acc0 = __builtin_amdgcn_mfma_f32_16x16x32_bf16(a0, breg[kt], acc0, 0, 0, 0);
      const int byteB = (mrow * 2048 + ((kt + 1) * 4 + (lane >> 4)) * 16) ^ rswz;
      bf16x8 a1 = *(const bf16x8*)((const char*)A_lds + byteB);
      acc1 = __builtin_amdgcn_mfma_f32_16x16x32_bf16(a1, breg[kt + 1], acc1, 0, 0, 0);
    }

    // ---- elementwise: C/D layout col=lane&15 (our n), row=(lane>>4)*4+r ----
    float g0 = acc0[0] + acc1[0] + bval;
    float g1 = acc0[1] + acc1[1] + bval;
    float g2 = acc0[2] + acc1[2] + bval;
    float g3 = acc0[3] + acc1[3] + bval;
    // activate by OWN type (i,f,o: sigmoid; g: tanh), then exchange
    float v0 = (tt == 2) ? fast_tanh(g0) : fast_sigmoid(g0);
    float v1 = (tt == 2) ? fast_tanh(g1) : fast_sigmoid(g1);
    float v2 = (tt == 2) ? fast_tanh(g2) : fast_sigmoid(g2);
    float v3 = (tt == 2) ? fast_tanh(g3) : fast_sigmoid(g3);

    float hv0, hv1, hv2, hv3;
#define CELL_R(vr, cr, hvr)                                                  \
    {                                                                        \
      float e1 = __shfl_xor(vr, 4, 64);                                      \
      float e2 = __shfl_xor(vr, 8, 64);                                      \
      float e3 = __shfl_xor(e1, 8, 64);                                      \
      float iv = pick4(tt,     vr, e1, e2, e3);                              \
      float fv = pick4(tt ^ 1, vr, e1, e2, e3);                              \
      float gv = pick4(tt ^ 2, vr, e1, e2, e3);                              \
      float ov = pick4(tt ^ 3, vr, e1, e2, e3);                              \
      cr = fv * cr + iv * gv;                                                \
      hvr = ov * fast_tanh(cr);                                              \
    }
    CELL_R(v0, c0, hv0)
    CELL_R(v1, c1, hv1)
    CELL_R(v2, c2, hv2)
    CELL_R(v3, c3, hv3)
#undef CELL_R

    // ---- stores: lane stores row m=4*(lane>>4)+tt, col hh ----
    const int m = 4 * (lane >> 4) + tt;
    const float hsel = pick4(tt, hv0, hv1, hv2, hv3);
    out[(size_t)t * (BATCH * HDIM) + (size_t)(b0 + m) * HDIM + hh] = hsel;

    // publish h_{t+1} as tagged u64 (tag = t+1), buffer parity (t+1)&1
    {
      unsigned hb = (unsigned)f2bf(hsel);
      unsigned ob = (unsigned)__shfl_xor((int)hb, 1, 64);
      if (!(lane & 1)) {
        uint64_t val = (uint64_t)(uint32_t)(t + 1)
                     | ((uint64_t)(hb | (ob << 16)) << 32);
        uint64_t* hnp = h_buf + ((size_t)((t + 1) & 1) * NGROUPS + group) * HB_U64_PER_GROUP
                      + m * (HDIM / 2) + (hh >> 1);
        __hip_atomic_store(hnp, val, __ATOMIC_RELAXED, __HIP_MEMORY_SCOPE_AGENT);
      }
    }

    __syncthreads();  // protect A_lds before next step's staging
  }
}

extern "C" void kernel_launch(void* const* d_in, const int* in_sizes, int n_in,
                              void* d_out, int out_size, void* d_ws, size_t ws_size,
                              hipStream_t stream) {
  const float* x    = (const float*)d_in[0];
  const float* w_ih = (const float*)d_in[1];
  const float* w_hh = (const float*)d_in[2];
  const float* b_ih = (const float*)d_in[3];
  const float* b_hh = (const float*)d_in[4];
  float* out = (float*)d_out;

  char* ws = (char*)d_ws;
  float* bias = (float*)ws;                          // 8KB
  uint64_t* h_buf = (uint64_t*)(ws + 8192);          // 256KB tagged pairs

  lstm_init<<<8, 256, 0, stream>>>(b_ih, b_hh, bias, h_buf);
  lstm_persistent<<<NWG, 256, 0, stream>>>(x, w_ih, w_hh, bias, h_buf, out);
}

// Round 3
// 2953.467 us; speedup vs baseline: 2.0020x; 1.2152x over previous
//
#include <hip/hip_runtime.h>
#include <stdint.h>

// LSTM B=64,T=512,I=512,H=512. out hs[T,B,H] fp32.
// Persistent: 4 batch-groups x 32 wgs (128 wgs, 256 thr). Each wg: 16 batch
// rows x 16 h-cols (all 4 gates). Weights in registers as bf16 MFMA
// fragments, TRANSPOSED-C form: acc = mfma(W_frag, X_frag) so each lane's
// 4 acc regs = gates {i,f,g,o} of one (batch,col) -> lane-local cell update.
// Per step: issue h-tag loads + x_{t+1} loads, x-part MFMAs overlap the
// poll, parallel-retry poll (reload ALL 16 per round), stage h, ONE
// __syncthreads, h-part MFMAs, elementwise, publish tagged h (relaxed
// agent-scope u64 [data:32|tag:32]). X and H LDS double-buffered.

#define BATCH 64
#define TSTEPS 512
#define IDIM 512
#define HDIM 512
#define WGS_PER_GROUP 32
#define NGROUPS 4
#define BB 16
#define NWG (WGS_PER_GROUP * NGROUPS)
#define HB_U64_PER_GROUP (BB * (HDIM / 2))   // 4096 u64 per buffer per group

typedef __attribute__((ext_vector_type(4))) float f32x4;
typedef __attribute__((ext_vector_type(8))) short bf16x8;

__device__ inline unsigned short f2bf(float f) {
  unsigned u = __builtin_bit_cast(unsigned, f);
  u = (u + 0x7fffu + ((u >> 16) & 1u)) >> 16;  // RNE
  return (unsigned short)u;
}
__device__ inline float fast_sigmoid(float x) { return 1.f / (1.f + __expf(-x)); }
__device__ inline float fast_tanh(float x) { return 1.f - 2.f / (__expf(2.f * x) + 1.f); }

__global__ void lstm_init(const float* __restrict__ b_ih, const float* __restrict__ b_hh,
                          float* __restrict__ bias, uint64_t* __restrict__ h_buf) {
  const int i = blockIdx.x * blockDim.x + threadIdx.x;
  if (i < 4 * HDIM) bias[i] = b_ih[i] + b_hh[i];
  // zero both tagged-h buffers (tag 0 never matches expected tag >= 1;
  // clears stale tags between graph replays)
  for (int j = i; j < 2 * NGROUPS * HB_U64_PER_GROUP; j += 2048) h_buf[j] = 0ull;
}

__global__ __launch_bounds__(256, 1)
void lstm_persistent(const float* __restrict__ x,
                     const float* __restrict__ w_ih,
                     const float* __restrict__ w_hh,
                     const float* __restrict__ bias,
                     uint64_t* h_buf,   // [2][NGROUPS][BB][HDIM/2] tagged pairs
                     float* __restrict__ out) {
  __shared__ unsigned short X_lds[2][16 * IDIM];   // 2 x 16KB, XOR-swizzled
  __shared__ unsigned short H_lds[2][16 * HDIM];   // 2 x 16KB, XOR-swizzled

  const int wg = blockIdx.x;
  const int group = wg >> 5;
  const int wgg = wg & 31;
  const int b0 = group * BB;
  const int h0 = wgg * 16;
  const int tid = threadIdx.x;
  const int wave = tid >> 6;
  const int lane = tid & 63;
  const int hi4 = lane >> 4;

  // ---- one-time: weight A-fragments (transposed-C form) ----
  // lane holds W[wrow = lane&15][k = kt*32 + hi4*8 + j]; tile-row wrow:
  // type = wrow&3, local h-col = wrow>>2  => acc regs r = gate types.
  const int nn = lane & 15;
  const int type = nn & 3;
  const int hcl = nn >> 2;
  const int grow = type * HDIM + h0 + wave * 4 + hcl;   // gate row in [0,2048)
  bf16x8 breg[32];
#pragma unroll
  for (int kt = 0; kt < 32; ++kt) {
    const int k = kt * 32 + hi4 * 8;
    const float* src = (k < IDIM) ? (w_ih + (size_t)grow * IDIM + k)
                                  : (w_hh + (size_t)grow * HDIM + (k - IDIM));
    bf16x8 v;
#pragma unroll
    for (int j = 0; j < 8; ++j) v[j] = (short)f2bf(src[j]);
    breg[kt] = v;
  }
  const int mycol = h0 + wave * 4 + hi4;   // this lane's h column
  const float bv0 = bias[0 * HDIM + mycol];
  const float bv1 = bias[1 * HDIM + mycol];
  const float bv2 = bias[2 * HDIM + mycol];
  const float bv3 = bias[3 * HDIM + mycol];

  // staging roles
  const int sm = tid >> 4;   // batch row 0..15
  const int sk = tid & 15;   // k-chunk of 32
  const int wswz = (sm & 7) << 4;
  const int mrow = lane & 15;             // B-operand row = batch
  const int rswz = (mrow & 7) << 4;

  // ---- prologue: stage x_0 -> X_lds[0] ----
  {
    const float* xp = x + ((size_t)(b0 + sm) * TSTEPS + 0) * IDIM + sk * 32;
#pragma unroll
    for (int q = 0; q < 4; ++q) {
      float4 fa = *(const float4*)(xp + q * 8);
      float4 fb = *(const float4*)(xp + q * 8 + 4);
      bf16x8 v;
      v[0] = (short)f2bf(fa.x); v[1] = (short)f2bf(fa.y);
      v[2] = (short)f2bf(fa.z); v[3] = (short)f2bf(fa.w);
      v[4] = (short)f2bf(fb.x); v[5] = (short)f2bf(fb.y);
      v[6] = (short)f2bf(fb.z); v[7] = (short)f2bf(fb.w);
      *(bf16x8*)((char*)&X_lds[0][0] + ((sm * 1024 + (sk * 4 + q) * 16) ^ wswz)) = v;
    }
  }
  __syncthreads();

  float c = 0.f;   // cell state for (batch=lane&15, col=mycol)

  for (int t = 0; t < TSTEPS; ++t) {
    const int cur = t & 1;

    // ---- issue h_t tag loads (critical path) ----
    uint64_t hu[16];
    const uint64_t* hp = h_buf + ((size_t)cur * NGROUPS + group) * HB_U64_PER_GROUP
                       + sm * (HDIM / 2) + sk * 16;
    if (t > 0) {
#pragma unroll
      for (int j = 0; j < 16; ++j)
        hu[j] = __hip_atomic_load(hp + j, __ATOMIC_RELAXED, __HIP_MEMORY_SCOPE_AGENT);
    }
    // ---- issue x_{t+1} loads ----
    float4 xf[8];
    if (t + 1 < TSTEPS) {
      const float* xp = x + ((size_t)(b0 + sm) * TSTEPS + (t + 1)) * IDIM + sk * 32;
#pragma unroll
      for (int q = 0; q < 8; ++q) xf[q] = *(const float4*)(xp + q * 4);
    }
    asm volatile("" ::: "memory");  // pin load issue before compute phase

    // ---- phase A: x-part MFMAs (kt 0..15) overlap the in-flight loads ----
    f32x4 acc0 = {0.f, 0.f, 0.f, 0.f}, acc1 = {0.f, 0.f, 0.f, 0.f};
#pragma unroll
    for (int kt = 0; kt < 16; kt += 2) {
      bf16x8 a0 = *(const bf16x8*)((const char*)&X_lds[cur][0] +
                    ((mrow * 1024 + (kt * 4 + hi4) * 16) ^ rswz));
      acc0 = __builtin_amdgcn_mfma_f32_16x16x32_bf16(breg[kt], a0, acc0, 0, 0, 0);
      bf16x8 a1 = *(const bf16x8*)((const char*)&X_lds[cur][0] +
                    ((mrow * 1024 + ((kt + 1) * 4 + hi4) * 16) ^ rswz));
      acc1 = __builtin_amdgcn_mfma_f32_16x16x32_bf16(breg[kt + 1], a1, acc1, 0, 0, 0);
    }

    // ---- phase B: parallel-retry poll, stage H and X_next ----
    if (t > 0) {
      while (true) {
        bool ok = true;
#pragma unroll
        for (int j = 0; j < 16; ++j) ok &= ((uint32_t)hu[j] == (uint32_t)t);
        if (ok) break;
#pragma unroll
        for (int j = 0; j < 16; ++j)   // reload ALL pending in parallel
          hu[j] = __hip_atomic_load(hp + j, __ATOMIC_RELAXED, __HIP_MEMORY_SCOPE_AGENT);
      }
#pragma unroll
      for (int q = 0; q < 4; ++q) {
        bf16x8 v;
#pragma unroll
        for (int jj = 0; jj < 4; ++jj) {
          uint32_t u = (uint32_t)(hu[q * 4 + jj] >> 32);
          v[jj * 2] = (short)(u & 0xffffu);
          v[jj * 2 + 1] = (short)(u >> 16);
        }
        *(bf16x8*)((char*)&H_lds[cur][0] + ((sm * 1024 + (sk * 4 + q) * 16) ^ wswz)) = v;
      }
    }
    if (t + 1 < TSTEPS) {
#pragma unroll
      for (int q = 0; q < 4; ++q) {
        float4 fa = xf[q * 2], fb = xf[q * 2 + 1];
        bf16x8 v;
        v[0] = (short)f2bf(fa.x); v[1] = (short)f2bf(fa.y);
        v[2] = (short)f2bf(fa.z); v[3] = (short)f2bf(fa.w);
        v[4] = (short)f2bf(fb.x); v[5] = (short)f2bf(fb.y);
        v[6] = (short)f2bf(fb.z); v[7] = (short)f2bf(fb.w);
        *(bf16x8*)((char*)&X_lds[cur ^ 1][0] + ((sm * 1024 + (sk * 4 + q) * 16) ^ wswz)) = v;
      }
    }
    __syncthreads();   // the ONLY barrier per step

    // ---- phase C: h-part MFMAs (kt 16..31) ----
    if (t > 0) {
#pragma unroll
      for (int kt = 0; kt < 16; kt += 2) {
        bf16x8 a0 = *(const bf16x8*)((const char*)&H_lds[cur][0] +
                      ((mrow * 1024 + (kt * 4 + hi4) * 16) ^ rswz));
        acc0 = __builtin_amdgcn_mfma_f32_16x16x32_bf16(breg[16 + kt], a0, acc0, 0, 0, 0);
        bf16x8 a1 = *(const bf16x8*)((const char*)&H_lds[cur][0] +
                      ((mrow * 1024 + ((kt + 1) * 4 + hi4) * 16) ^ rswz));
        acc1 = __builtin_amdgcn_mfma_f32_16x16x32_bf16(breg[17 + kt], a1, acc1, 0, 0, 0);
      }
    }

    // ---- elementwise: lane-local gates i,f,g,o in acc regs 0..3 ----
    const float gi = acc0[0] + acc1[0] + bv0;
    const float gf = acc0[1] + acc1[1] + bv1;
    const float gg = acc0[2] + acc1[2] + bv2;
    const float go = acc0[3] + acc1[3] + bv3;
    c = fast_sigmoid(gf) * c + fast_sigmoid(gi) * fast_tanh(gg);
    const float hval = fast_sigmoid(go) * fast_tanh(c);

    // ---- publish h_{t+1} (tag t+1) FIRST, then out store ----
    if (t + 1 < TSTEPS) {
      unsigned hb = (unsigned)f2bf(hval);
      unsigned pb = (unsigned)__shfl_xor((int)hb, 16, 64);  // partner col +-1
      if ((hi4 & 1) == 0) {
        uint64_t val = (uint64_t)(uint32_t)(t + 1)
                     | ((uint64_t)(hb | (pb << 16)) << 32);
        uint64_t* hnp = h_buf + ((size_t)((t + 1) & 1) * NGROUPS + group) * HB_U64_PER_GROUP
                      + (size_t)(lane & 15) * (HDIM / 2) + (mycol >> 1);
        __hip_atomic_store(hnp, val, __ATOMIC_RELAXED, __HIP_MEMORY_SCOPE_AGENT);
      }
    } else {
      // keep shuffle count uniform (not required, but harmless): nothing
    }
    out[(size_t)t * (BATCH * HDIM) + (size_t)(b0 + (lane & 15)) * HDIM + mycol] = hval;
  }
}

extern "C" void kernel_launch(void* const* d_in, const int* in_sizes, int n_in,
                              void* d_out, int out_size, void* d_ws, size_t ws_size,
                              hipStream_t stream) {
  const float* x    = (const float*)d_in[0];
  const float* w_ih = (const float*)d_in[1];
  const float* w_hh = (const float*)d_in[2];
  const float* b_ih = (const float*)d_in[3];
  const float* b_hh = (const float*)d_in[4];
  float* out = (float*)d_out;

  char* ws = (char*)d_ws;
  float* bias = (float*)ws;                          // 8KB
  uint64_t* h_buf = (uint64_t*)(ws + 8192);          // 256KB tagged pairs

  lstm_init<<<8, 256, 0, stream>>>(b_ih, b_hh, bias, h_buf);
  lstm_persistent<<<NWG, 256, 0, stream>>>(x, w_ih, w_hh, bias, h_buf, out);
}